// Round 1
// baseline (237.337 us; speedup 1.0000x reference)
//
#include <hip/hip_runtime.h>
#include <math.h>

// Problem constants (from reference)
#define BB 16
#define VV 6890
#define NFF 13776
#define HH 512
#define WW 512
// SIGMA = 1e-4 -> 1/SIGMA = 1e4

// Stage 1: face normal + atomic scatter-add into per-vertex normal accumulator.
__global__ __launch_bounds__(256) void k_face_scatter(const float* __restrict__ verts,
                                                      const int* __restrict__ faces,
                                                      float* __restrict__ vn) {
    int i = blockIdx.x * 256 + threadIdx.x;
    if (i >= BB * NFF) return;
    int b = i / NFF;
    int f = i - b * NFF;
    int i0 = faces[3 * f + 0];
    int i1 = faces[3 * f + 1];
    int i2 = faces[3 * f + 2];
    const float* vb = verts + (size_t)b * (VV * 3);
    float ax = vb[3 * i0 + 0], ay = vb[3 * i0 + 1], az = vb[3 * i0 + 2];
    float bx = vb[3 * i1 + 0], by = vb[3 * i1 + 1], bz = vb[3 * i1 + 2];
    float cx = vb[3 * i2 + 0], cy = vb[3 * i2 + 1], cz = vb[3 * i2 + 2];
    float e1x = bx - ax, e1y = by - ay, e1z = bz - az;
    float e2x = cx - ax, e2y = cy - ay, e2z = cz - az;
    float nx = e1y * e2z - e1z * e2y;
    float ny = e1z * e2x - e1x * e2z;
    float nz = e1x * e2y - e1y * e2x;
    float* vnb = vn + (size_t)b * (VV * 3);
    atomicAdd(&vnb[3 * i0 + 0], nx); atomicAdd(&vnb[3 * i0 + 1], ny); atomicAdd(&vnb[3 * i0 + 2], nz);
    atomicAdd(&vnb[3 * i1 + 0], nx); atomicAdd(&vnb[3 * i1 + 1], ny); atomicAdd(&vnb[3 * i1 + 2], nz);
    atomicAdd(&vnb[3 * i2 + 0], nx); atomicAdd(&vnb[3 * i2 + 1], ny); atomicAdd(&vnb[3 * i2 + 2], nz);
}

// Stage 2: normalize vertex normals (vn / max(||vn||, 1e-6))
__global__ __launch_bounds__(256) void k_normalize(float* __restrict__ vn) {
    int i = blockIdx.x * 256 + threadIdx.x;
    if (i >= BB * VV) return;
    float x = vn[3 * i + 0], y = vn[3 * i + 1], z = vn[3 * i + 2];
    float n = sqrtf(x * x + y * y + z * z);
    float inv = 1.0f / fmaxf(n, 1e-6f);
    vn[3 * i + 0] = x * inv;
    vn[3 * i + 1] = y * inv;
    vn[3 * i + 2] = z * inv;
}

// Stage 3: face_attr_sum[b,f] = sum of the 3 normalized vertex normals
__global__ __launch_bounds__(256) void k_face_sum(const float* __restrict__ vn,
                                                  const int* __restrict__ faces,
                                                  float* __restrict__ fas) {
    int i = blockIdx.x * 256 + threadIdx.x;
    if (i >= BB * NFF) return;
    int b = i / NFF;
    int f = i - b * NFF;
    int i0 = faces[3 * f + 0], i1 = faces[3 * f + 1], i2 = faces[3 * f + 2];
    const float* vnb = vn + (size_t)b * (VV * 3);
    fas[3 * i + 0] = vnb[3 * i0 + 0] + vnb[3 * i1 + 0] + vnb[3 * i2 + 0];
    fas[3 * i + 1] = vnb[3 * i0 + 1] + vnb[3 * i1 + 1] + vnb[3 * i2 + 1];
    fas[3 * i + 2] = vnb[3 * i0 + 2] + vnb[3 * i1 + 2] + vnb[3 * i2 + 2];
}

// Stage 4: per-pixel gather + normalize + alpha. Output float4 per pixel.
__global__ __launch_bounds__(256) void k_pixel(const int* __restrict__ p2f,
                                               const float* __restrict__ dists,
                                               const float* __restrict__ fas,
                                               float4* __restrict__ out) {
    int i = blockIdx.x * 256 + threadIdx.x;
    if (i >= BB * HH * WW) return;
    int b = i >> 18;  // H*W = 262144 = 2^18
    int f = p2f[i];
    float d = dists[i];
    float px = 0.f, py = 0.f, pz = 0.f;
    float prob = 0.f;
    if (f >= 0) {
        int fc = f < (NFF - 1) ? f : (NFF - 1);
        const float* p = fas + ((size_t)b * NFF + fc) * 3;
        px = p[0]; py = p[1]; pz = p[2];
        // prob = sigmoid(-d/SIGMA) = 1/(1+exp(d/SIGMA)); masked to 0 when invalid
        prob = 1.0f / (1.0f + expf(d * 1.0e4f));
    }
    float n2 = px * px + py * py + pz * pz;
    float inv = 1.0f / fmaxf(sqrtf(n2), 1e-12f);
    float hitadd = (n2 > 0.f) ? 0.f : 1.0f;  // +1 on all channels when no hit
    float4 o;
    o.x = px * inv + hitadd;
    o.y = py * inv + hitadd;
    o.z = pz * inv + hitadd;
    o.w = 1.0f - prob;
    out[i] = o;
}

extern "C" void kernel_launch(void* const* d_in, const int* in_sizes, int n_in,
                              void* d_out, int out_size, void* d_ws, size_t ws_size,
                              hipStream_t stream) {
    const float* verts = (const float*)d_in[0];
    // d_in[1] = zbuf: dead in the reference's returned value -> never read
    const float* dists = (const float*)d_in[2];
    const int* faces   = (const int*)d_in[3];
    const int* p2f     = (const int*)d_in[4];

    float* vn  = (float*)d_ws;                    // B*V*3 floats = 1.3 MB
    float* fas = vn + (size_t)BB * VV * 3;        // B*NF*3 floats = 2.6 MB

    hipMemsetAsync(vn, 0, sizeof(float) * (size_t)BB * VV * 3, stream);

    int nfaces = BB * NFF;
    k_face_scatter<<<(nfaces + 255) / 256, 256, 0, stream>>>(verts, faces, vn);
    k_normalize<<<(BB * VV + 255) / 256, 256, 0, stream>>>(vn);
    k_face_sum<<<(nfaces + 255) / 256, 256, 0, stream>>>(vn, faces, fas);

    int npix = BB * HH * WW;  // 4,194,304; divisible by 256
    k_pixel<<<npix / 256, 256, 0, stream>>>(p2f, dists, fas, (float4*)d_out);
}

// Round 3
// 175.504 us; speedup vs baseline: 1.3523x; 1.3523x over previous
//
#include <hip/hip_runtime.h>
#include <math.h>

// Problem constants (from reference)
#define BB 16
#define VV 6890
#define NFF 13776
#define HH 512
#define WW 512
// SIGMA = 1e-4 -> 1/SIGMA = 1e4

typedef float nf4 __attribute__((ext_vector_type(4)));  // native vec4 for nontemporal store

// ---------------------------------------------------------------------------
// Stage 1: per-(batch,face) face normal -> fn4[b*NFF+f] (float4, w unused)
// ---------------------------------------------------------------------------
__global__ __launch_bounds__(256) void k_fn(const float* __restrict__ verts,
                                            const int* __restrict__ faces,
                                            float4* __restrict__ fn4) {
    int i = blockIdx.x * 256 + threadIdx.x;
    if (i >= BB * NFF) return;
    int b = i / NFF;
    int f = i - b * NFF;
    int i0 = faces[3 * f + 0];
    int i1 = faces[3 * f + 1];
    int i2 = faces[3 * f + 2];
    const float* vb = verts + (size_t)b * (VV * 3);
    float ax = vb[3 * i0 + 0], ay = vb[3 * i0 + 1], az = vb[3 * i0 + 2];
    float bx = vb[3 * i1 + 0], by = vb[3 * i1 + 1], bz = vb[3 * i1 + 2];
    float cx = vb[3 * i2 + 0], cy = vb[3 * i2 + 1], cz = vb[3 * i2 + 2];
    float e1x = bx - ax, e1y = by - ay, e1z = bz - az;
    float e2x = cx - ax, e2y = cy - ay, e2z = cz - az;
    float4 n;
    n.x = e1y * e2z - e1z * e2y;
    n.y = e1z * e2x - e1x * e2z;
    n.z = e1x * e2y - e1y * e2x;
    n.w = 0.f;
    fn4[i] = n;
}

// ---------------------------------------------------------------------------
// CSR build: histogram of vertex degrees (int atomics, 41K total)
// ---------------------------------------------------------------------------
__global__ __launch_bounds__(256) void k_count(const int* __restrict__ faces,
                                               int* __restrict__ counts) {
    int f = blockIdx.x * 256 + threadIdx.x;
    if (f >= NFF) return;
    atomicAdd(&counts[faces[3 * f + 0]], 1);
    atomicAdd(&counts[faces[3 * f + 1]], 1);
    atomicAdd(&counts[faces[3 * f + 2]], 1);
}

// Single-block exclusive scan of counts[VV] in place; counts[VV] = total.
#define SCAN_T 1024
__global__ __launch_bounds__(SCAN_T) void k_scan(int* __restrict__ counts) {
    __shared__ int part[SCAN_T];
    const int CH = (VV + SCAN_T - 1) / SCAN_T;  // 7
    int t = threadIdx.x;
    int base = t * CH;
    int local = 0;
    for (int k = 0; k < CH; k++) {
        int idx = base + k;
        if (idx < VV) local += counts[idx];
    }
    part[t] = local;
    __syncthreads();
    // Hillis-Steele inclusive scan over 1024 partials
    for (int off = 1; off < SCAN_T; off <<= 1) {
        int v = part[t];
        int add = (t >= off) ? part[t - off] : 0;
        __syncthreads();
        part[t] = v + add;
        __syncthreads();
    }
    int running = (t == 0) ? 0 : part[t - 1];
    for (int k = 0; k < CH; k++) {
        int idx = base + k;
        if (idx < VV) {
            int c = counts[idx];
            counts[idx] = running;  // exclusive offset
            running += c;
        }
    }
    if (t == 0) counts[VV] = part[SCAN_T - 1];  // total
}

// Fill adjacency: adj[offset[v] + cursor[v]++] = f
__global__ __launch_bounds__(256) void k_fill(const int* __restrict__ faces,
                                              const int* __restrict__ offsets,
                                              int* __restrict__ cursor,
                                              int* __restrict__ adj) {
    int f = blockIdx.x * 256 + threadIdx.x;
    if (f >= NFF) return;
    for (int c = 0; c < 3; c++) {
        int v = faces[3 * f + c];
        int pos = offsets[v] + atomicAdd(&cursor[v], 1);
        adj[pos] = f;
    }
}

// ---------------------------------------------------------------------------
// Stage 2: per-(batch,vertex) gather adjacent face normals, normalize
// ---------------------------------------------------------------------------
__global__ __launch_bounds__(256) void k_vn(const float4* __restrict__ fn4,
                                            const int* __restrict__ offsets,
                                            const int* __restrict__ adj,
                                            float4* __restrict__ vn4) {
    int i = blockIdx.x * 256 + threadIdx.x;
    if (i >= BB * VV) return;
    int b = i / VV;
    int v = i - b * VV;
    int s = offsets[v], e = offsets[v + 1];
    float x = 0.f, y = 0.f, z = 0.f;
    const float4* fnb = fn4 + (size_t)b * NFF;
    for (int j = s; j < e; j++) {
        float4 n = fnb[adj[j]];
        x += n.x; y += n.y; z += n.z;
    }
    float nrm = sqrtf(x * x + y * y + z * z);
    float inv = 1.0f / fmaxf(nrm, 1e-6f);
    float4 o; o.x = x * inv; o.y = y * inv; o.z = z * inv; o.w = 0.f;
    vn4[i] = o;
}

// ---------------------------------------------------------------------------
// Stage 3: face_attr_sum[b,f] = sum of the 3 normalized vertex normals
// ---------------------------------------------------------------------------
__global__ __launch_bounds__(256) void k_face_sum(const float4* __restrict__ vn4,
                                                  const int* __restrict__ faces,
                                                  float4* __restrict__ fas4) {
    int i = blockIdx.x * 256 + threadIdx.x;
    if (i >= BB * NFF) return;
    int b = i / NFF;
    int f = i - b * NFF;
    int i0 = faces[3 * f + 0], i1 = faces[3 * f + 1], i2 = faces[3 * f + 2];
    const float4* vnb = vn4 + (size_t)b * VV;
    float4 a = vnb[i0], bb = vnb[i1], cc = vnb[i2];
    float4 o;
    o.x = a.x + bb.x + cc.x;
    o.y = a.y + bb.y + cc.y;
    o.z = a.z + bb.z + cc.z;
    o.w = 0.f;
    fas4[i] = o;
}

// ---------------------------------------------------------------------------
// Stage 4: per-pixel gather + normalize + alpha. 2 pixels per thread.
// ---------------------------------------------------------------------------
__device__ __forceinline__ nf4 pixel_one(int f, float d, const float4* __restrict__ fasb) {
    float px = 0.f, py = 0.f, pz = 0.f, prob = 0.f;
    if (f >= 0) {
        int fc = f < (NFF - 1) ? f : (NFF - 1);
        float4 p = fasb[fc];
        px = p.x; py = p.y; pz = p.z;
        prob = 1.0f / (1.0f + __expf(d * 1.0e4f));  // sigmoid(-d/SIGMA)
    }
    float n2 = px * px + py * py + pz * pz;
    float inv = 1.0f / fmaxf(sqrtf(n2), 1e-12f);
    float hitadd = (n2 > 0.f) ? 0.f : 1.0f;
    nf4 o;
    o.x = px * inv + hitadd;
    o.y = py * inv + hitadd;
    o.z = pz * inv + hitadd;
    o.w = 1.0f - prob;
    return o;
}

__global__ __launch_bounds__(256) void k_pixel(const int* __restrict__ p2f,
                                               const float* __restrict__ dists,
                                               const float4* __restrict__ fas4,
                                               nf4* __restrict__ out) {
    int i = (blockIdx.x * 256 + threadIdx.x) * 2;
    if (i >= BB * HH * WW) return;
    int b = i >> 18;  // H*W = 2^18; pair never crosses batch boundary
    int2 ff = *(const int2*)(p2f + i);
    float2 dd = *(const float2*)(dists + i);
    const float4* fasb = fas4 + (size_t)b * NFF;
    nf4 o0 = pixel_one(ff.x, dd.x, fasb);
    nf4 o1 = pixel_one(ff.y, dd.y, fasb);
    __builtin_nontemporal_store(o0, &out[i]);
    __builtin_nontemporal_store(o1, &out[i + 1]);
}

// ---------------------------------------------------------------------------
extern "C" void kernel_launch(void* const* d_in, const int* in_sizes, int n_in,
                              void* d_out, int out_size, void* d_ws, size_t ws_size,
                              hipStream_t stream) {
    const float* verts = (const float*)d_in[0];
    // d_in[1] = zbuf: dead in the reference's returned value -> never read
    const float* dists = (const float*)d_in[2];
    const int* faces   = (const int*)d_in[3];
    const int* p2f     = (const int*)d_in[4];

    // Workspace layout (16B-aligned chunks)
    char* w = (char*)d_ws;
    float4* fn4  = (float4*)w;                         w += (size_t)BB * NFF * 16;   // 3.53 MB
    float4* vn4  = (float4*)w;                         w += (size_t)BB * VV * 16;    // 1.76 MB
    float4* fas4 = (float4*)w;                         w += (size_t)BB * NFF * 16;   // 3.53 MB
    int* counts  = (int*)w;                            w += ((VV + 1) * 4 + 12) / 16 * 16;
    int* cursor  = (int*)w;                            w += (VV * 4 + 15) / 16 * 16;
    int* adj     = (int*)w;                            w += NFF * 3 * 4;

    // Zero the histogram + cursor (contiguous region)
    (void)hipMemsetAsync(counts, 0, (size_t)((VV + 1) + VV) * sizeof(int) + 32, stream);

    int nbf = BB * NFF;  // 220416
    int nbv = BB * VV;   // 110240

    k_fn<<<(nbf + 255) / 256, 256, 0, stream>>>(verts, faces, fn4);
    k_count<<<(NFF + 255) / 256, 256, 0, stream>>>(faces, counts);
    k_scan<<<1, SCAN_T, 0, stream>>>(counts);
    k_fill<<<(NFF + 255) / 256, 256, 0, stream>>>(faces, counts, cursor, adj);
    k_vn<<<(nbv + 255) / 256, 256, 0, stream>>>(fn4, counts, adj, vn4);
    k_face_sum<<<(nbf + 255) / 256, 256, 0, stream>>>(vn4, faces, fas4);

    int npix = BB * HH * WW;  // 4,194,304
    k_pixel<<<npix / 2 / 256, 256, 0, stream>>>(p2f, dists, fas4, (nf4*)d_out);
}